// Round 1
// baseline (585.636 us; speedup 1.0000x reference)
//
#include <hip/hip_runtime.h>
#include <hip/hip_bf16.h>
#include <stdint.h>

// Problem dims (fixed)
constexpr int BDIM = 8192;
constexpr int INDIM = 4096;
constexpr int OUTDIM = 4096;

typedef __attribute__((ext_vector_type(8))) short bf16x8;
typedef __attribute__((ext_vector_type(4))) float f32x4;

__device__ __forceinline__ uint16_t f2bf_rne(float f) {
  union { float f; uint32_t u; } v; v.f = f;
  uint32_t r = v.u + 0x7fffu + ((v.u >> 16) & 1u);
  return (uint16_t)(r >> 16);
}

__device__ __forceinline__ void gload_lds16(const void* g, void* l) {
  __builtin_amdgcn_global_load_lds(
      (const __attribute__((address_space(1))) void*)g,
      (__attribute__((address_space(3))) void*)l, 16, 0, 0);
}

// ---------------- kernel 1: lin_w -> bf16 ----------------
__global__ __launch_bounds__(256) void k_conv_w(const float* __restrict__ w,
                                                uint16_t* __restrict__ wb) {
  const int n4 = (OUTDIM * INDIM) / 4;
  for (int i = blockIdx.x * 256 + threadIdx.x; i < n4; i += gridDim.x * 256) {
    float4 v = ((const float4*)w)[i];
    ushort4 o;
    o.x = f2bf_rne(v.x); o.y = f2bf_rne(v.y);
    o.z = f2bf_rne(v.z); o.w = f2bf_rne(v.w);
    ((ushort4*)wb)[i] = o;
  }
}

// ---------- kernel 2: x -> bf16, fused haar (proj channels 0..4 in fp32) ----------
__global__ __launch_bounds__(256) void k_conv_x_haar(
    const float* __restrict__ x, const float* __restrict__ proj_w,
    const float* __restrict__ proj_b, const float* __restrict__ scales,
    const float* __restrict__ trans, uint16_t* __restrict__ xb,
    float* __restrict__ haar) {
  const int row = blockIdx.x;
  const int tid = threadIdx.x;
  const float4* xr = (const float4*)(x + (size_t)row * INDIM);
  ushort4* xbr = (ushort4*)(xb + (size_t)row * INDIM);
  float acc[5] = {0.f, 0.f, 0.f, 0.f, 0.f};
#pragma unroll
  for (int c = 0; c < 4; ++c) {
    int i4 = tid + c * 256;
    float4 v = xr[i4];
    ushort4 o;
    o.x = f2bf_rne(v.x); o.y = f2bf_rne(v.y);
    o.z = f2bf_rne(v.z); o.w = f2bf_rne(v.w);
    xbr[i4] = o;
#pragma unroll
    for (int j = 0; j < 5; ++j) {
      float4 p = ((const float4*)(proj_w + (size_t)j * INDIM))[i4];
      acc[j] += v.x * p.x + v.y * p.y + v.z * p.z + v.w * p.w;
    }
  }
  __shared__ float wred[4][5];
  const int lane = tid & 63, w = tid >> 6;
#pragma unroll
  for (int j = 0; j < 5; ++j) {
    float v = acc[j];
#pragma unroll
    for (int off = 32; off; off >>= 1) v += __shfl_down(v, off, 64);
    if (lane == 0) wred[w][j] = v;
  }
  __syncthreads();
  if (tid < 5) {
    float p = wred[0][tid] + wred[1][tid] + wred[2][tid] + wred[3][tid] + proj_b[tid];
    float sx = (p - trans[tid]) / scales[tid];
    float h = 0.f;
    if (sx >= 0.f && sx < 0.5f) h = 1.f;
    else if (sx >= 0.5f && sx < 1.f) h = -1.f;
    haar[(size_t)row * 5 + tid] = h;
  }
}

// ---------- kernel 3: db scalars -> c[4096] and W5[5][4096] (one block) ----------
__global__ __launch_bounds__(256) void k_db_c(
    const float* __restrict__ x, const float* __restrict__ proj_w,
    const float* __restrict__ proj_b, const float* __restrict__ scales,
    const float* __restrict__ lin_b, const float* __restrict__ comb_w,
    const float* __restrict__ comb_b, float* __restrict__ cvec,
    float* __restrict__ W5) {
  __shared__ float wred[4][11];
  __shared__ float dbs[11];
  const int tid = threadIdx.x, lane = tid & 63, w = tid >> 6;
  float acc[11];
#pragma unroll
  for (int j = 0; j < 11; ++j) acc[j] = 0.f;
  for (int r = 0; r < 4; ++r) {
    const float4* xr = (const float4*)(x + (size_t)r * INDIM);
    for (int c = tid; c < INDIM / 4; c += 256) {
      float4 v = xr[c];
#pragma unroll
      for (int j = 0; j < 11; ++j) {
        float4 p = ((const float4*)(proj_w + (size_t)(j + 5) * INDIM))[c];
        acc[j] += v.x * p.x + v.y * p.y + v.z * p.z + v.w * p.w;
      }
    }
  }
#pragma unroll
  for (int j = 0; j < 11; ++j) {
    float v = acc[j];
#pragma unroll
    for (int off = 32; off; off >>= 1) v += __shfl_down(v, off, 64);
    if (lane == 0) wred[w][j] = v;
  }
  __syncthreads();
  if (tid == 0) {
    const float DB2[4] = {-0.1294095225512604f, -0.2241438680420134f,
                          0.8365163037378079f, -0.4829629131445341f};
    const float DB4[8] = {-0.0074578275060427f, -0.0233534968567756f,
                          0.0218081502370024f,  0.1323683939878645f,
                          -0.0197721859913265f, -0.4461007108737368f,
                          0.5055922216746659f,  -0.1629171572809054f};
    for (int j = 0; j < 11; ++j) {
      float sum = wred[0][j] + wred[1][j] + wred[2][j] + wred[3][j];
      float val = sum * 0.25f + proj_b[j + 5];
      float sc = scales[j + 5];
      float sf = 2.f / (1.f + expf(-sc));
      const float* filt = (j < 5) ? DB2 : DB4;
      int L = (j < 5) ? 4 : 8;
      float ssin = 0.f, sabs = 0.f;
      for (int i = 0; i < L; ++i) {
        float fi = filt[i] * sf;
        ssin += sinf(fi * 5.0f);
        sabs += fabsf(fi);
      }
      dbs[j] = val * (ssin / (float)L) / (sabs * 0.1f);
    }
  }
  __syncthreads();
  for (int o = tid; o < OUTDIM; o += 256) {
    const float* cw = comb_w + (size_t)o * 16;
    float cc = lin_b[o] + comb_b[o];
#pragma unroll
    for (int j = 0; j < 11; ++j) cc += dbs[j] * cw[5 + j];
    cvec[o] = cc;
#pragma unroll
    for (int j = 0; j < 5; ++j) W5[j * OUTDIM + o] = cw[j];
  }
}

// ---------------- kernel 4: bf16 MFMA GEMM (m97 structure) ----------------
// direct[b,o] = sum_k xb[b,k] * wb[o,k]  -> C (fp32, d_out)
__global__ __launch_bounds__(256) void k_gemm(const uint16_t* __restrict__ A,
                                              const uint16_t* __restrict__ Bw,
                                              float* __restrict__ C) {
  constexpr int N = OUTDIM, K = INDIM;
  __shared__ uint16_t As[128 * 32];
  __shared__ uint16_t Bs[128 * 32];
  const int tid = threadIdx.x;
  const int wid = tid >> 6, lane = tid & 63;
  const int l15 = lane & 15, kh = lane >> 4;
  const int wr = wid >> 1, wc = wid & 1;
  const int nwg = gridDim.x;
  const int bid = blockIdx.x;
  const int wg = (bid & 7) * (nwg >> 3) + (bid >> 3);  // XCD swizzle (nwg%8==0)
  constexpr int NB = N / 128;
  const int mblk = wg / NB, nblk = wg % NB;
  const size_t arow = (size_t)mblk * 128, brow = (size_t)nblk * 128;

  const uint16_t* aS0 = A + (arow + (tid >> 2)) * K + (tid & 3) * 8;
  const uint16_t* aS1 = A + (arow + 64 + (tid >> 2)) * K + (tid & 3) * 8;
  const uint16_t* bS0 = Bw + (brow + (tid >> 2)) * K + (tid & 3) * 8;
  const uint16_t* bS1 = Bw + (brow + 64 + (tid >> 2)) * K + (tid & 3) * 8;
  char* aL0 = (char*)As + wid * 1024;
  char* aL1 = (char*)As + 4096 + wid * 1024;
  char* bL0 = (char*)Bs + wid * 1024;
  char* bL1 = (char*)Bs + 4096 + wid * 1024;

  f32x4 acc[4][4];
#pragma unroll
  for (int m = 0; m < 4; ++m)
#pragma unroll
    for (int n = 0; n < 4; ++n) acc[m][n] = (f32x4){0.f, 0.f, 0.f, 0.f};

  for (int kt = 0; kt < K; kt += 32) {
    __syncthreads();  // previous compute done before overwrite
    gload_lds16(aS0 + kt, aL0);
    gload_lds16(aS1 + kt, aL1);
    gload_lds16(bS0 + kt, bL0);
    gload_lds16(bS1 + kt, bL1);
    __syncthreads();  // staging drained (compiler emits vmcnt(0) before barrier)
    bf16x8 af[4], bfr[4];
#pragma unroll
    for (int m = 0; m < 4; ++m)
      af[m] = *(const bf16x8*)&As[(wr * 64 + m * 16 + l15) * 32 + kh * 8];
#pragma unroll
    for (int n = 0; n < 4; ++n)
      bfr[n] = *(const bf16x8*)&Bs[(wc * 64 + n * 16 + l15) * 32 + kh * 8];
#pragma unroll
    for (int m = 0; m < 4; ++m)
#pragma unroll
      for (int n = 0; n < 4; ++n)
        acc[m][n] = __builtin_amdgcn_mfma_f32_16x16x32_bf16(af[m], bfr[n],
                                                            acc[m][n], 0, 0, 0);
  }
  // epilogue: C/D layout col=lane&15, row=(lane>>4)*4+reg (m89-verified)
#pragma unroll
  for (int m = 0; m < 4; ++m) {
#pragma unroll
    for (int n = 0; n < 4; ++n) {
      int col = (int)brow + wc * 64 + n * 16 + l15;
      size_t r0 = arow + wr * 64 + m * 16 + kh * 4;
#pragma unroll
      for (int j = 0; j < 4; ++j)
        C[(r0 + j) * N + col] = acc[m][n][j];
    }
  }
}

// ---------------- kernel 5: wave-path add + LayerNorm (in place on d_out) ----------------
__global__ __launch_bounds__(256) void k_ln(
    float* __restrict__ y, const float* __restrict__ haar,
    const float* __restrict__ cvec, const float* __restrict__ W5,
    const float* __restrict__ g, const float* __restrict__ beta) {
  const int row = blockIdx.x;
  const int tid = threadIdx.x;
  const float h0 = haar[(size_t)row * 5 + 0];
  const float h1 = haar[(size_t)row * 5 + 1];
  const float h2 = haar[(size_t)row * 5 + 2];
  const float h3 = haar[(size_t)row * 5 + 3];
  const float h4 = haar[(size_t)row * 5 + 4];
  float4* yr = (float4*)(y + (size_t)row * OUTDIM);
  float4 vals[4];
  float s = 0.f, s2 = 0.f;
#pragma unroll
  for (int c = 0; c < 4; ++c) {
    int i4 = tid + c * 256;
    float4 d = yr[i4];
    float4 cv = ((const float4*)cvec)[i4];
    float4 w0 = ((const float4*)(W5 + 0 * OUTDIM))[i4];
    float4 w1 = ((const float4*)(W5 + 1 * OUTDIM))[i4];
    float4 w2 = ((const float4*)(W5 + 2 * OUTDIM))[i4];
    float4 w3 = ((const float4*)(W5 + 3 * OUTDIM))[i4];
    float4 w4 = ((const float4*)(W5 + 4 * OUTDIM))[i4];
    float4 t;
    t.x = d.x + cv.x + h0 * w0.x + h1 * w1.x + h2 * w2.x + h3 * w3.x + h4 * w4.x;
    t.y = d.y + cv.y + h0 * w0.y + h1 * w1.y + h2 * w2.y + h3 * w3.y + h4 * w4.y;
    t.z = d.z + cv.z + h0 * w0.z + h1 * w1.z + h2 * w2.z + h3 * w3.z + h4 * w4.z;
    t.w = d.w + cv.w + h0 * w0.w + h1 * w1.w + h2 * w2.w + h3 * w3.w + h4 * w4.w;
    vals[c] = t;
    s += t.x + t.y + t.z + t.w;
    s2 += t.x * t.x + t.y * t.y + t.z * t.z + t.w * t.w;
  }
  const int lane = tid & 63, w = tid >> 6;
#pragma unroll
  for (int off = 32; off; off >>= 1) {
    s += __shfl_down(s, off, 64);
    s2 += __shfl_down(s2, off, 64);
  }
  __shared__ float rs[4], rs2[4];
  __shared__ float smu, sinv;
  if (lane == 0) { rs[w] = s; rs2[w] = s2; }
  __syncthreads();
  if (tid == 0) {
    float S = rs[0] + rs[1] + rs[2] + rs[3];
    float S2 = rs2[0] + rs2[1] + rs2[2] + rs2[3];
    float mu = S / (float)OUTDIM;
    float var = S2 / (float)OUTDIM - mu * mu;
    smu = mu;
    sinv = rsqrtf(var + 1e-5f);
  }
  __syncthreads();
  const float mu = smu, inv = sinv;
#pragma unroll
  for (int c = 0; c < 4; ++c) {
    int i4 = tid + c * 256;
    float4 gg = ((const float4*)g)[i4];
    float4 bb = ((const float4*)beta)[i4];
    float4 t = vals[c];
    float4 o;
    o.x = (t.x - mu) * inv * gg.x + bb.x;
    o.y = (t.y - mu) * inv * gg.y + bb.y;
    o.z = (t.z - mu) * inv * gg.z + bb.z;
    o.w = (t.w - mu) * inv * gg.w + bb.w;
    yr[i4] = o;
  }
}

// ---------------- launch ----------------
extern "C" void kernel_launch(void* const* d_in, const int* in_sizes, int n_in,
                              void* d_out, int out_size, void* d_ws, size_t ws_size,
                              hipStream_t stream) {
  const float* x      = (const float*)d_in[0];
  const float* lin_w  = (const float*)d_in[1];
  const float* lin_b  = (const float*)d_in[2];
  const float* proj_w = (const float*)d_in[3];
  const float* proj_b = (const float*)d_in[4];
  const float* scales = (const float*)d_in[5];
  const float* trans  = (const float*)d_in[6];
  const float* comb_w = (const float*)d_in[7];
  const float* comb_b = (const float*)d_in[8];
  const float* ln_g   = (const float*)d_in[9];
  const float* ln_b   = (const float*)d_in[10];
  float* out = (float*)d_out;

  char* ws = (char*)d_ws;
  uint16_t* xb  = (uint16_t*)ws;                                // 67,108,864 B
  uint16_t* wb  = (uint16_t*)(ws + 67108864);                   // 33,554,432 B
  float*    haar = (float*)(ws + 100663296);                    // 163,840 B
  float*    cvec = (float*)(ws + 100827136);                    // 16,384 B
  float*    W5   = (float*)(ws + 100843520);                    // 81,920 B

  k_conv_w<<<2048, 256, 0, stream>>>(lin_w, wb);
  k_conv_x_haar<<<BDIM, 256, 0, stream>>>(x, proj_w, proj_b, scales, trans, xb, haar);
  k_db_c<<<1, 256, 0, stream>>>(x, proj_w, proj_b, scales, lin_b, comb_w, comb_b,
                                cvec, W5);
  k_gemm<<<(BDIM / 128) * (OUTDIM / 128), 256, 0, stream>>>(xb, wb, out);
  k_ln<<<BDIM, 256, 0, stream>>>(out, haar, cvec, W5, ln_g, ln_b);
}

// Round 2
// 378.572 us; speedup vs baseline: 1.5470x; 1.5470x over previous
//
#include <hip/hip_runtime.h>
#include <hip/hip_bf16.h>
#include <stdint.h>

// Problem dims (fixed)
constexpr int BDIM = 8192;
constexpr int INDIM = 4096;
constexpr int OUTDIM = 4096;

typedef __attribute__((ext_vector_type(8))) short bf16x8;
typedef __attribute__((ext_vector_type(4))) float f32x4;

__device__ __forceinline__ uint16_t f2bf_rne(float f) {
  union { float f; uint32_t u; } v; v.f = f;
  uint32_t r = v.u + 0x7fffu + ((v.u >> 16) & 1u);
  return (uint16_t)(r >> 16);
}

__device__ __forceinline__ void gload_lds16(const void* g, void* l) {
  __builtin_amdgcn_global_load_lds(
      (const __attribute__((address_space(1))) void*)g,
      (__attribute__((address_space(3))) void*)l, 16, 0, 0);
}

// ---------------- kernel 1: lin_w -> bf16 ----------------
__global__ __launch_bounds__(256) void k_conv_w(const float* __restrict__ w,
                                                uint16_t* __restrict__ wb) {
  const int n4 = (OUTDIM * INDIM) / 4;
  for (int i = blockIdx.x * 256 + threadIdx.x; i < n4; i += gridDim.x * 256) {
    float4 v = ((const float4*)w)[i];
    ushort4 o;
    o.x = f2bf_rne(v.x); o.y = f2bf_rne(v.y);
    o.z = f2bf_rne(v.z); o.w = f2bf_rne(v.w);
    ((ushort4*)wb)[i] = o;
  }
}

// ---------- kernel 2: x -> bf16, fused haar (proj channels 0..4 in fp32) ----------
__global__ __launch_bounds__(256) void k_conv_x_haar(
    const float* __restrict__ x, const float* __restrict__ proj_w,
    const float* __restrict__ proj_b, const float* __restrict__ scales,
    const float* __restrict__ trans, uint16_t* __restrict__ xb,
    float* __restrict__ haar) {
  const int row = blockIdx.x;
  const int tid = threadIdx.x;
  const float4* xr = (const float4*)(x + (size_t)row * INDIM);
  ushort4* xbr = (ushort4*)(xb + (size_t)row * INDIM);
  float acc[5] = {0.f, 0.f, 0.f, 0.f, 0.f};
#pragma unroll
  for (int c = 0; c < 4; ++c) {
    int i4 = tid + c * 256;
    float4 v = xr[i4];
    ushort4 o;
    o.x = f2bf_rne(v.x); o.y = f2bf_rne(v.y);
    o.z = f2bf_rne(v.z); o.w = f2bf_rne(v.w);
    xbr[i4] = o;
#pragma unroll
    for (int j = 0; j < 5; ++j) {
      float4 p = ((const float4*)(proj_w + (size_t)j * INDIM))[i4];
      acc[j] += v.x * p.x + v.y * p.y + v.z * p.z + v.w * p.w;
    }
  }
  __shared__ float wred[4][5];
  const int lane = tid & 63, w = tid >> 6;
#pragma unroll
  for (int j = 0; j < 5; ++j) {
    float v = acc[j];
#pragma unroll
    for (int off = 32; off; off >>= 1) v += __shfl_down(v, off, 64);
    if (lane == 0) wred[w][j] = v;
  }
  __syncthreads();
  if (tid < 5) {
    float p = wred[0][tid] + wred[1][tid] + wred[2][tid] + wred[3][tid] + proj_b[tid];
    float sx = (p - trans[tid]) / scales[tid];
    float h = 0.f;
    if (sx >= 0.f && sx < 0.5f) h = 1.f;
    else if (sx >= 0.5f && sx < 1.f) h = -1.f;
    haar[(size_t)row * 5 + tid] = h;
  }
}

// ---------- kernel 3: db scalars -> c[4096] and W5[5][4096] (one block) ----------
__global__ __launch_bounds__(256) void k_db_c(
    const float* __restrict__ x, const float* __restrict__ proj_w,
    const float* __restrict__ proj_b, const float* __restrict__ scales,
    const float* __restrict__ lin_b, const float* __restrict__ comb_w,
    const float* __restrict__ comb_b, float* __restrict__ cvec,
    float* __restrict__ W5) {
  __shared__ float wred[4][11];
  __shared__ float dbs[11];
  const int tid = threadIdx.x, lane = tid & 63, w = tid >> 6;
  float acc[11];
#pragma unroll
  for (int j = 0; j < 11; ++j) acc[j] = 0.f;
  for (int r = 0; r < 4; ++r) {
    const float4* xr = (const float4*)(x + (size_t)r * INDIM);
    for (int c = tid; c < INDIM / 4; c += 256) {
      float4 v = xr[c];
#pragma unroll
      for (int j = 0; j < 11; ++j) {
        float4 p = ((const float4*)(proj_w + (size_t)(j + 5) * INDIM))[c];
        acc[j] += v.x * p.x + v.y * p.y + v.z * p.z + v.w * p.w;
      }
    }
  }
#pragma unroll
  for (int j = 0; j < 11; ++j) {
    float v = acc[j];
#pragma unroll
    for (int off = 32; off; off >>= 1) v += __shfl_down(v, off, 64);
    if (lane == 0) wred[w][j] = v;
  }
  __syncthreads();
  if (tid == 0) {
    const float DB2[4] = {-0.1294095225512604f, -0.2241438680420134f,
                          0.8365163037378079f, -0.4829629131445341f};
    const float DB4[8] = {-0.0074578275060427f, -0.0233534968567756f,
                          0.0218081502370024f,  0.1323683939878645f,
                          -0.0197721859913265f, -0.4461007108737368f,
                          0.5055922216746659f,  -0.1629171572809054f};
    for (int j = 0; j < 11; ++j) {
      float sum = wred[0][j] + wred[1][j] + wred[2][j] + wred[3][j];
      float val = sum * 0.25f + proj_b[j + 5];
      float sc = scales[j + 5];
      float sf = 2.f / (1.f + expf(-sc));
      const float* filt = (j < 5) ? DB2 : DB4;
      int L = (j < 5) ? 4 : 8;
      float ssin = 0.f, sabs = 0.f;
      for (int i = 0; i < L; ++i) {
        float fi = filt[i] * sf;
        ssin += sinf(fi * 5.0f);
        sabs += fabsf(fi);
      }
      dbs[j] = val * (ssin / (float)L) / (sabs * 0.1f);
    }
  }
  __syncthreads();
  for (int o = tid; o < OUTDIM; o += 256) {
    const float* cw = comb_w + (size_t)o * 16;
    float cc = lin_b[o] + comb_b[o];
#pragma unroll
    for (int j = 0; j < 11; ++j) cc += dbs[j] * cw[5 + j];
    cvec[o] = cc;
#pragma unroll
    for (int j = 0; j < 5; ++j) W5[j * OUTDIM + o] = cw[j];
  }
}

// ---------------- kernel 4: bf16 MFMA GEMM, 256x256 8-phase template ----------------
// direct[b,o] = sum_k xb[b,k] * wb[o,k]  -> C (fp32, d_out)
// T2 (st-swizzle via pre-swizzled global src + swizzled ds_read) +
// T3/T4 (8-phase, counted vmcnt(4) at phases 4/8 only) + T5 (setprio) + T1 (XCD swizzle)

#define BARX() __builtin_amdgcn_s_barrier()
#define LGKM0() do { asm volatile("s_waitcnt lgkmcnt(0)" ::: "memory"); \
                     __builtin_amdgcn_sched_barrier(0); } while (0)
#define VM4() asm volatile("s_waitcnt vmcnt(4)" ::: "memory")

#define STAGE_A(t, h) do { \
  const char* _s = aSrc + (size_t)(h) * 128 * 8192 + (size_t)((t) & 63) * 128; \
  char* _l = sA + ((t) & 1) * 32768 + (h) * 16384 + ldsStage; \
  gload_lds16(_s, _l); gload_lds16(_s + 64 * 8192, _l + 8192); } while (0)

#define STAGE_B(t, h) do { \
  const char* _s = bSrc + (size_t)(h) * 128 * 8192 + (size_t)((t) & 63) * 128; \
  char* _l = sB + ((t) & 1) * 32768 + (h) * 16384 + ldsStage; \
  gload_lds16(_s, _l); gload_lds16(_s + 64 * 8192, _l + 8192); } while (0)

#define RDA4(buf, mb) do { const char* _p = sA + (buf) * 32768; \
  _Pragma("unroll") for (int _m = 0; _m < 4; ++_m) { \
    ar[_m][0] = *(const bf16x8*)(_p + (aoff + ((mb) + _m) * 2048)); \
    ar[_m][1] = *(const bf16x8*)(_p + ((aoff ^ 64) + ((mb) + _m) * 2048)); } } while (0)

#define RDB2(buf, arr, nb) do { const char* _p = sB + (buf) * 32768; \
  _Pragma("unroll") for (int _n = 0; _n < 2; ++_n) { \
    arr[_n][0] = *(const bf16x8*)(_p + (boff + ((nb) + _n) * 2048)); \
    arr[_n][1] = *(const bf16x8*)(_p + ((boff ^ 64) + ((nb) + _n) * 2048)); } } while (0)

#define MF8(mb, arrB, nb) do { \
  __builtin_amdgcn_s_setprio(1); \
  _Pragma("unroll") for (int _m = 0; _m < 4; ++_m) \
  _Pragma("unroll") for (int _n = 0; _n < 2; ++_n) { \
    acc[(mb) + _m][(nb) + _n] = __builtin_amdgcn_mfma_f32_16x16x32_bf16( \
        ar[_m][0], arrB[_n][0], acc[(mb) + _m][(nb) + _n], 0, 0, 0); \
    acc[(mb) + _m][(nb) + _n] = __builtin_amdgcn_mfma_f32_16x16x32_bf16( \
        ar[_m][1], arrB[_n][1], acc[(mb) + _m][(nb) + _n], 0, 0, 0); } \
  __builtin_amdgcn_s_setprio(0); } while (0)

__global__ __launch_bounds__(512, 2) void k_gemm(const uint16_t* __restrict__ A,
                                                 const uint16_t* __restrict__ Bw,
                                                 float* __restrict__ C) {
  constexpr int K = INDIM;   // 4096, row = 8192 bytes
  constexpr int N = OUTDIM;  // 4096
  extern __shared__ char smem[];  // 128 KiB: A bufs [0,64K), B bufs [64K,128K)
  char* sA = smem;
  char* sB = smem + 65536;

  const int tid = threadIdx.x;
  const int wid = tid >> 6;
  const int lane = tid & 63;
  const int l15 = lane & 15;
  const int kh = lane >> 4;  // 0..3
  const int wm = wid >> 2;   // 0..1
  const int wn = wid & 3;    // 0..3

  // T1: XCD-aware swizzle (nwg = 512, %8 == 0)
  const int nwg = gridDim.x;
  const int bid = blockIdx.x;
  const int wg = (bid & 7) * (nwg >> 3) + (bid >> 3);
  constexpr int NBN = N / 256;  // 16
  const int mblk = wg / NBN, nblk = wg % NBN;
  const size_t arow = (size_t)mblk * 256, brow = (size_t)nblk * 256;

  // staging: linear LDS dest, inverse-swizzled global source (rule #21)
  const int srow = tid >> 3;                                  // 0..63
  const int scol = ((tid & 7) * 16) ^ ((srow & 7) << 4);      // swizzled byte col
  const char* aSrc = (const char*)A + (arow + srow) * 8192 + scol;
  const char* bSrc = (const char*)Bw + (brow + srow) * 8192 + scol;
  const int ldsStage = wid * 1024;

  // fragment ds_read offsets (same XOR swizzle on read side)
  const int col0 = (kh * 16) ^ ((l15 & 7) << 4);
  const int aoff = (wm * 128 + l15) * 128 + col0;
  const int boff = (wn * 64 + l15) * 128 + col0;

  f32x4 acc[8][4];
#pragma unroll
  for (int m = 0; m < 8; ++m)
#pragma unroll
    for (int n = 0; n < 4; ++n) acc[m][n] = (f32x4){0.f, 0.f, 0.f, 0.f};
  bf16x8 ar[4][2], b01[2][2], b23[2][2];

  // prologue: tile0 (B-lo,B-hi,A-lo,A-hi) + tile1 (B-lo,B-hi); keep tile1-B in flight
  STAGE_B(0, 0); STAGE_B(0, 1); STAGE_A(0, 0); STAGE_A(0, 1);
  STAGE_B(1, 0); STAGE_B(1, 1);
  VM4(); BARX();

  for (int it = 0; it < K / 128; ++it) {
    const int t1 = it * 2 + 1, t2 = it * 2 + 2, t3 = it * 2 + 3;
    // P1: compute buf0 quadrant (m0-3 x n0-1); stage t1 A-lo
    RDA4(0, 0); RDB2(0, b01, 0);
    STAGE_A(t1, 0);
    BARX(); LGKM0(); MF8(0, b01, 0); BARX();
    // P2: (m0-3 x n2-3); stage t1 A-hi
    RDB2(0, b23, 2);
    STAGE_A(t1, 1);
    BARX(); LGKM0(); MF8(0, b23, 2); BARX();
    // P3: (m4-7 x n0-1); stage t2 B-lo
    RDA4(0, 4);
    STAGE_B(t2, 0);
    BARX(); LGKM0(); MF8(4, b01, 0); BARX();
    // P4: (m4-7 x n2-3); stage t2 B-hi; counted wait -> tile t1 fully arrived
    STAGE_B(t2, 1);
    BARX(); LGKM0(); MF8(4, b23, 2);
    VM4(); BARX();
    // P5: compute buf1 (m0-3 x n0-1); stage t2 A-lo
    RDA4(1, 0); RDB2(1, b01, 0);
    STAGE_A(t2, 0);
    BARX(); LGKM0(); MF8(0, b01, 0); BARX();
    // P6: (m0-3 x n2-3); stage t2 A-hi
    RDB2(1, b23, 2);
    STAGE_A(t2, 1);
    BARX(); LGKM0(); MF8(0, b23, 2); BARX();
    // P7: (m4-7 x n0-1); stage t3 B-lo
    RDA4(1, 4);
    STAGE_B(t3, 0);
    BARX(); LGKM0(); MF8(4, b01, 0); BARX();
    // P8: (m4-7 x n2-3); stage t3 B-hi; counted wait -> tile t2 fully arrived
    STAGE_B(t3, 1);
    BARX(); LGKM0(); MF8(4, b23, 2);
    VM4(); BARX();
  }

  // epilogue: C/D layout col=lane&15, row=(lane>>4)*4+reg (m89-verified)
  const size_t crow0 = arow + (size_t)wm * 128;
  const int ccol0 = (int)brow + wn * 64;
#pragma unroll
  for (int m = 0; m < 8; ++m) {
#pragma unroll
    for (int n = 0; n < 4; ++n) {
      float* cp = C + (crow0 + m * 16 + kh * 4) * N + ccol0 + n * 16 + l15;
#pragma unroll
      for (int j = 0; j < 4; ++j) cp[(size_t)j * N] = acc[m][n][j];
    }
  }
}

// ---------------- kernel 5: wave-path add + LayerNorm (in place on d_out) ----------------
__global__ __launch_bounds__(256) void k_ln(
    float* __restrict__ y, const float* __restrict__ haar,
    const float* __restrict__ cvec, const float* __restrict__ W5,
    const float* __restrict__ g, const float* __restrict__ beta) {
  const int row = blockIdx.x;
  const int tid = threadIdx.x;
  const float h0 = haar[(size_t)row * 5 + 0];
  const float h1 = haar[(size_t)row * 5 + 1];
  const float h2 = haar[(size_t)row * 5 + 2];
  const float h3 = haar[(size_t)row * 5 + 3];
  const float h4 = haar[(size_t)row * 5 + 4];
  float4* yr = (float4*)(y + (size_t)row * OUTDIM);
  float4 vals[4];
  float s = 0.f, s2 = 0.f;
#pragma unroll
  for (int c = 0; c < 4; ++c) {
    int i4 = tid + c * 256;
    float4 d = yr[i4];
    float4 cv = ((const float4*)cvec)[i4];
    float4 w0 = ((const float4*)(W5 + 0 * OUTDIM))[i4];
    float4 w1 = ((const float4*)(W5 + 1 * OUTDIM))[i4];
    float4 w2 = ((const float4*)(W5 + 2 * OUTDIM))[i4];
    float4 w3 = ((const float4*)(W5 + 3 * OUTDIM))[i4];
    float4 w4 = ((const float4*)(W5 + 4 * OUTDIM))[i4];
    float4 t;
    t.x = d.x + cv.x + h0 * w0.x + h1 * w1.x + h2 * w2.x + h3 * w3.x + h4 * w4.x;
    t.y = d.y + cv.y + h0 * w0.y + h1 * w1.y + h2 * w2.y + h3 * w3.y + h4 * w4.y;
    t.z = d.z + cv.z + h0 * w0.z + h1 * w1.z + h2 * w2.z + h3 * w3.z + h4 * w4.z;
    t.w = d.w + cv.w + h0 * w0.w + h1 * w1.w + h2 * w2.w + h3 * w3.w + h4 * w4.w;
    vals[c] = t;
    s += t.x + t.y + t.z + t.w;
    s2 += t.x * t.x + t.y * t.y + t.z * t.z + t.w * t.w;
  }
  const int lane = tid & 63, w = tid >> 6;
#pragma unroll
  for (int off = 32; off; off >>= 1) {
    s += __shfl_down(s, off, 64);
    s2 += __shfl_down(s2, off, 64);
  }
  __shared__ float rs[4], rs2[4];
  __shared__ float smu, sinv;
  if (lane == 0) { rs[w] = s; rs2[w] = s2; }
  __syncthreads();
  if (tid == 0) {
    float S = rs[0] + rs[1] + rs[2] + rs[3];
    float S2 = rs2[0] + rs2[1] + rs2[2] + rs2[3];
    float mu = S / (float)OUTDIM;
    float var = S2 / (float)OUTDIM - mu * mu;
    smu = mu;
    sinv = rsqrtf(var + 1e-5f);
  }
  __syncthreads();
  const float mu = smu, inv = sinv;
#pragma unroll
  for (int c = 0; c < 4; ++c) {
    int i4 = tid + c * 256;
    float4 gg = ((const float4*)g)[i4];
    float4 bb = ((const float4*)beta)[i4];
    float4 t = vals[c];
    float4 o;
    o.x = (t.x - mu) * inv * gg.x + bb.x;
    o.y = (t.y - mu) * inv * gg.y + bb.y;
    o.z = (t.z - mu) * inv * gg.z + bb.z;
    o.w = (t.w - mu) * inv * gg.w + bb.w;
    yr[i4] = o;
  }
}

// ---------------- launch ----------------
extern "C" void kernel_launch(void* const* d_in, const int* in_sizes, int n_in,
                              void* d_out, int out_size, void* d_ws, size_t ws_size,
                              hipStream_t stream) {
  const float* x      = (const float*)d_in[0];
  const float* lin_w  = (const float*)d_in[1];
  const float* lin_b  = (const float*)d_in[2];
  const float* proj_w = (const float*)d_in[3];
  const float* proj_b = (const float*)d_in[4];
  const float* scales = (const float*)d_in[5];
  const float* trans  = (const float*)d_in[6];
  const float* comb_w = (const float*)d_in[7];
  const float* comb_b = (const float*)d_in[8];
  const float* ln_g   = (const float*)d_in[9];
  const float* ln_b   = (const float*)d_in[10];
  float* out = (float*)d_out;

  char* ws = (char*)d_ws;
  uint16_t* xb  = (uint16_t*)ws;                                // 67,108,864 B
  uint16_t* wb  = (uint16_t*)(ws + 67108864);                   // 33,554,432 B
  float*    haar = (float*)(ws + 100663296);                    // 163,840 B
  float*    cvec = (float*)(ws + 100827136);                    // 16,384 B
  float*    W5   = (float*)(ws + 100843520);                    // 81,920 B

  // allow 128 KiB dynamic LDS for the GEMM (host-side attribute, capture-safe)
  hipFuncSetAttribute((const void*)k_gemm,
                      hipFuncAttributeMaxDynamicSharedMemorySize, 131072);

  k_conv_w<<<2048, 256, 0, stream>>>(lin_w, wb);
  k_conv_x_haar<<<BDIM, 256, 0, stream>>>(x, proj_w, proj_b, scales, trans, xb, haar);
  k_db_c<<<1, 256, 0, stream>>>(x, proj_w, proj_b, scales, lin_b, comb_w, comb_b,
                                cvec, W5);
  k_gemm<<<(BDIM / 256) * (OUTDIM / 256), 512, 131072, stream>>>(xb, wb, out);
  k_ln<<<BDIM, 256, 0, stream>>>(out, haar, cvec, W5, ln_g, ln_b);
}